// Round 1
// baseline (622.130 us; speedup 1.0000x reference)
//
#include <hip/hip_runtime.h>

#define N_BATCH 2048
#define HW 49          // H*W = 7*7
#define CCH 512        // channels
#define PADP 52        // padded p-dim (multiple of 4) for float4 attn rows

// ---------------------------------------------------------------------------
// Kernel A: transpose attn[n][p][q] -> attnT[n][q][p] (p padded to 52, zeros)
// Reads coalesced, LDS transpose, writes coalesced. ~41 MB total traffic.
// ---------------------------------------------------------------------------
__global__ __launch_bounds__(256) void transpose_attn(
    const float* __restrict__ attn, float* __restrict__ attnT)
{
    __shared__ float lds[HW * HW];
    const int n = blockIdx.x;
    const int tid = threadIdx.x;

    const float* a = attn + (size_t)n * (HW * HW);
    for (int i = tid; i < HW * HW; i += 256) lds[i] = a[i];
    __syncthreads();

    float* t = attnT + (size_t)n * (HW * PADP);
    for (int j = tid; j < HW * PADP; j += 256) {
        const int q = j / PADP;
        const int p = j - q * PADP;
        // lds read stride 49 words (odd) -> conflict-free
        t[j] = (p < HW) ? lds[p * HW + q] : 0.0f;
    }
}

// ---------------------------------------------------------------------------
// Kernel B: one block per n. Thread owns c0 = 2*tid, c0+1.
//   acc[p] += attnT[q][p] * D[q][c]   (attnT rows are wave-uniform float4s)
// Epilogue stages y through LDS (2 chunks of 256 channels) so the final
// out = x + alpha*y copy is flat float4 coalesced.
// ---------------------------------------------------------------------------
__global__ __launch_bounds__(256, 3) void fused_bmm_tn_add(
    const float* __restrict__ x, const float* __restrict__ D,
    const float* __restrict__ attnT, const float* __restrict__ alpha_p,
    float* __restrict__ out)
{
    __shared__ float ylds[256 * HW];   // 49 KB -> 3 blocks/CU
    const int n = blockIdx.x;
    const int tid = threadIdx.x;
    const int c0 = tid * 2;

    float acc0[PADP], acc1[PADP];
    #pragma unroll
    for (int p = 0; p < PADP; ++p) { acc0[p] = 0.f; acc1[p] = 0.f; }

    const float* Dn = D + (size_t)n * (HW * CCH);
    const float4* An = (const float4*)(attnT + (size_t)n * (HW * PADP));

    // software-pipelined D load (one float2 in flight)
    float2 d2 = *(const float2*)(Dn + c0);
    #pragma unroll 1
    for (int q = 0; q < HW; ++q) {
        float2 dnx = (q < HW - 1)
            ? *(const float2*)(Dn + (size_t)(q + 1) * CCH + c0)
            : make_float2(0.f, 0.f);
        const float4* Aq = An + q * (PADP / 4);
        #pragma unroll
        for (int j = 0; j < PADP / 4; ++j) {
            const float4 av = Aq[j];              // wave-uniform -> s_load
            acc0[4*j+0] += av.x * d2.x;  acc1[4*j+0] += av.x * d2.y;
            acc0[4*j+1] += av.y * d2.x;  acc1[4*j+1] += av.y * d2.y;
            acc0[4*j+2] += av.z * d2.x;  acc1[4*j+2] += av.z * d2.y;
            acc0[4*j+3] += av.w * d2.x;  acc1[4*j+3] += av.w * d2.y;
        }
        d2 = dnx;
    }

    const float alpha = alpha_p[0];
    const size_t nbase = (size_t)n * (CCH * HW);

    #pragma unroll 1
    for (int ch = 0; ch < 2; ++ch) {
        __syncthreads();   // protect previous chunk's LDS reads
        // owners of this chunk's 256 channels write their acc into LDS
        if (tid >= ch * 128 && tid < ch * 128 + 128) {
            const int cl = c0 - ch * 256;          // 0..254, even
            #pragma unroll
            for (int p = 0; p < HW; ++p) {
                ylds[cl * HW + p]       = acc0[p];
                ylds[(cl + 1) * HW + p] = acc1[p];
            }
        }
        __syncthreads();
        // flat coalesced copy: out = x + alpha*y  (layouts match exactly)
        const float4* x4 = (const float4*)(x + nbase + (size_t)ch * (256 * HW));
        float4*       o4 = (float4*)(out + nbase + (size_t)ch * (256 * HW));
        const float4* y4 = (const float4*)ylds;
        for (int i = tid; i < (256 * HW) / 4; i += 256) {
            const float4 xv = x4[i];
            const float4 yv = y4[i];
            float4 ov;
            ov.x = xv.x + alpha * yv.x;
            ov.y = xv.y + alpha * yv.y;
            ov.z = xv.z + alpha * yv.z;
            ov.w = xv.w + alpha * yv.w;
            o4[i] = ov;
        }
    }
}

extern "C" void kernel_launch(void* const* d_in, const int* in_sizes, int n_in,
                              void* d_out, int out_size, void* d_ws, size_t ws_size,
                              hipStream_t stream) {
    const float* x     = (const float*)d_in[0];   // [2048,512,7,7]
    const float* attn  = (const float*)d_in[1];   // [2048,49,49]
    const float* Dm    = (const float*)d_in[2];   // [2048,49,512]
    const float* alpha = (const float*)d_in[3];   // [1]
    float* out = (float*)d_out;

    float* attnT = (float*)d_ws;   // needs 2048*49*52*4 = ~20.9 MB of ws

    transpose_attn<<<N_BATCH, 256, 0, stream>>>(attn, attnT);
    fused_bmm_tn_add<<<N_BATCH, 256, 0, stream>>>(x, Dm, attnT, alpha, out);
}